// Round 10
// baseline (154.772 us; speedup 1.0000x reference)
//
#include <hip/hip_runtime.h>

typedef __bf16 bf16x8 __attribute__((ext_vector_type(8)));
typedef float f32x16 __attribute__((ext_vector_type(16)));

#define N_EMB 4096
#define DIM 64
#define NCHUNK 128            // 4096 entries / 32 per chunk
#define NSETS 16              // 16 sets x 8 chunks; block owns one set
#define NW 4                  // waves per block
#define NC 2                  // chunks per wave, register-resident
#define T_TILES 16            // x-tiles (32 rows) per row-group
#define RPRG (T_TILES * 32)   // 512 rows per row-group
#define BIAS 0.0625f          // distances > 0 -> uint order == float order (R4-R9)

__device__ __forceinline__ unsigned int umin32(unsigned int a, unsigned int b) {
    return a < b ? a : b;
}
__device__ __forceinline__ unsigned int umin3(unsigned int a, unsigned int b,
                                              unsigned int c) {
    return umin32(umin32(a, b), c);    // fuses to v_min3_u32
}
__device__ __forceinline__ void gload_lds16(const void* g, void* l) {
    __builtin_amdgcn_global_load_lds(
        (const __attribute__((address_space(1))) unsigned int*)g,
        (__attribute__((address_space(3))) unsigned int*)l, 16, 0, 0);
}

// ---------------- prep: W-pack + a5-norm-frag + x-pack + counter zero ----------------
// Layouts validated R2-R9:
//  Wp[(g*4+s)*64+l][e] = bf16(-2 W[g*32+l%32][s*16+(l/32)*8+e])   (A-frag linear)
//  a5p[g*64+l] = {bf16(||W[g*32+l]||^2+BIAS),0..} for l<32 else 0 (a5 x e0 fold)
//  xp[gt*256+s*64+l][e] = bf16(x[gt*32+l%32][s*16+(l/32)*8+e])    (B-frag linear)
__global__ void prep(const float* __restrict__ w, const float* __restrict__ x,
                     bf16x8* __restrict__ Wp, bf16x8* __restrict__ a5p,
                     bf16x8* __restrict__ xp, int* __restrict__ cnt,
                     int nrows, int nrg) {
    int id = blockIdx.x * blockDim.x + threadIdx.x;
    if (id < NCHUNK * 64) {
        if (id < nrg) cnt[id] = 0;                 // zero rg counters each replay
        int g = id >> 6, l = id & 63;
        int hi = l >> 5;
        const float* wr = w + (size_t)((g << 5) + (l & 31)) * DIM + hi * 8;
        float ss = 0.f;
#pragma unroll
        for (int s = 0; s < 4; ++s) {
            const float4* p = (const float4*)(wr + s * 16);
            float4 v0 = p[0], v1 = p[1];
            ss += v0.x*v0.x + v0.y*v0.y + v0.z*v0.z + v0.w*v0.w;
            ss += v1.x*v1.x + v1.y*v1.y + v1.z*v1.z + v1.w*v1.w;
            bf16x8 o;
            o[0]=(__bf16)(-2.f*v0.x); o[1]=(__bf16)(-2.f*v0.y);
            o[2]=(__bf16)(-2.f*v0.z); o[3]=(__bf16)(-2.f*v0.w);
            o[4]=(__bf16)(-2.f*v1.x); o[5]=(__bf16)(-2.f*v1.y);
            o[6]=(__bf16)(-2.f*v1.z); o[7]=(__bf16)(-2.f*v1.w);
            Wp[(g * 4 + s) * 64 + l] = o;
        }
        ss += __shfl_xor(ss, 32, 64);
        bf16x8 a5 = {};
        if (l < 32) a5[0] = (__bf16)(ss + BIAS);
        a5p[g * 64 + l] = a5;
    } else {
        int id2 = id - NCHUNK * 64;
        int gt = id2 >> 6, l = id2 & 63;
        if (gt < nrows / 32) {
            int row = gt * 32 + (l & 31);
            const float* xr = x + (size_t)row * DIM + (l >> 5) * 8;
#pragma unroll
            for (int s = 0; s < 4; ++s) {
                const float4* p = (const float4*)(xr + s * 16);
                float4 v0 = p[0], v1 = p[1];
                bf16x8 o;
                o[0]=(__bf16)v0.x; o[1]=(__bf16)v0.y; o[2]=(__bf16)v0.z; o[3]=(__bf16)v0.w;
                o[4]=(__bf16)v1.x; o[5]=(__bf16)v1.y; o[6]=(__bf16)v1.z; o[7]=(__bf16)v1.w;
                xp[(size_t)gt * 256 + s * 64 + l] = o;
            }
        }
    }
}

// ---------------- main: W-regs, x via LDS ring, fused merge + epilogue ----------------
__global__ void __launch_bounds__(256) vq_main(
    const bf16x8* __restrict__ Wp, const bf16x8* __restrict__ a5p,
    const bf16x8* __restrict__ xp, const float* __restrict__ x,
    const float* __restrict__ w, unsigned int* __restrict__ partial,
    int* __restrict__ cnt, float* __restrict__ qout, float* __restrict__ lout,
    int nrows) {
    __shared__ bf16x8 buf[2][256];                 // 8 KB x-tile ring
    __shared__ unsigned int wmerge[NW][RPRG];      // 8 KB per-wave winners
    __shared__ unsigned int sentry[RPRG];          // 2 KB final entries
    __shared__ int slast;

    const int tid  = threadIdx.x;
    const int wv   = tid >> 6;
    const int lane = tid & 63;
    const int li   = lane & 31;
    const int hi   = lane >> 5;
    const int bid  = blockIdx.x;
    // swizzle: all 16 set-blocks of a row-group share bid%8 (-> same XCD if %8 rr)
    const int set  = (bid >> 3) & (NSETS - 1);
    const int rg   = ((bid >> 7) << 3) | (bid & 7);
    const int tbase = rg * T_TILES;

    // ---- W: this wave's 2 chunks, loaded once, register-resident ----
    bf16x8 a[NC][5];
#pragma unroll
    for (int ck = 0; ck < NC; ++ck) {
        int c = set * (NW * NC) + wv * NC + ck;
        const bf16x8* ap = Wp + (size_t)c * 256 + lane;
        a[ck][0] = ap[0]; a[ck][1] = ap[64]; a[ck][2] = ap[128]; a[ck][3] = ap[192];
        a[ck][4] = a5p[(size_t)c * 64 + lane];
    }
    bf16x8 xone = {};
    if (hi == 0) xone[0] = (__bf16)1.0f;           // B5 = e_0
    const f32x16 zacc = {};

    #define STAGE(tt) gload_lds16((const char*)(xp + (size_t)(tbase + (tt)) * 256) + tid * 16, \
                                  (char*)&buf[(tt) & 1][wv * 64])
    STAGE(0);
    __syncthreads();                               // drains vmcnt; tile 0 ready

#pragma unroll
    for (int t = 0; t < T_TILES; ++t) {
        if (t + 1 < T_TILES) STAGE(t + 1);         // only VMEM op in loop
        const bf16x8* bv = &buf[t & 1][0];
        bf16x8 b0 = bv[lane], b1 = bv[64 + lane], b2 = bv[128 + lane], b3 = bv[192 + lane];

        unsigned int best = 0xFFFFFFFFu;
#pragma unroll
        for (int ck = 0; ck < NC; ++ck) {
            f32x16 acc = __builtin_amdgcn_mfma_f32_32x32x16_bf16(a[ck][4], xone, zacc, 0, 0, 0);
            acc = __builtin_amdgcn_mfma_f32_32x32x16_bf16(a[ck][0], b0, acc, 0, 0, 0);
            acc = __builtin_amdgcn_mfma_f32_32x32x16_bf16(a[ck][1], b1, acc, 0, 0, 0);
            acc = __builtin_amdgcn_mfma_f32_32x32x16_bf16(a[ck][2], b2, acc, 0, 0, 0);
            acc = __builtin_amdgcn_mfma_f32_32x32x16_bf16(a[ck][3], b3, acc, 0, 0, 0);
            unsigned int tb[16];
#pragma unroll
            for (int r = 0; r < 16; ++r)
                tb[r] = (__builtin_bit_cast(unsigned int, acc[r]) & 0xFFFFFFC0u)
                        | ((unsigned int)ck << 4) | (unsigned int)r;
            unsigned int g0 = umin3(tb[0], tb[1], tb[2]);
            unsigned int g1 = umin3(tb[3], tb[4], tb[5]);
            unsigned int g2 = umin3(tb[6], tb[7], tb[8]);
            unsigned int g3 = umin3(tb[9], tb[10], tb[11]);
            unsigned int g4 = umin3(tb[12], tb[13], tb[14]);
            best = umin3(best, umin3(g0, g1, g2), umin3(g3, g4, tb[15]));
        }
        best |= (unsigned int)hi << 5;
        unsigned int ob = (unsigned int)__shfl_xor((int)best, 32, 64);
        best = umin32(best, ob);
        // reconstruct 12-bit entry; pack dist|entry; winner -> LDS (not vmcnt-counted)
        unsigned int r5 = best & 15u, ck2 = (best >> 4) & 1u, hh = (best >> 5) & 1u;
        unsigned int cg = (unsigned int)(set * (NW * NC) + wv * NC) + ck2;
        unsigned int entry = cg * 32 + (r5 & 3u) + ((r5 >> 2) << 3) + (hh << 2);
        if (lane < 32) wmerge[wv][t * 32 + li] = (best & 0xFFFFF000u) | entry;
        __syncthreads();                           // tile t+1 landed; buf[t&1] free
    }
    #undef STAGE

    // ---- cross-wave merge -> per-(rg,set) partial (2KB store, L2) ----
    unsigned int* pg = partial + ((size_t)rg * NSETS + set) * RPRG;
    for (int rr = tid; rr < RPRG; rr += 256) {
        unsigned int m0 = wmerge[0][rr], m1 = wmerge[1][rr];
        unsigned int m2 = wmerge[2][rr], m3 = wmerge[3][rr];
        pg[rr] = umin32(umin32(m0, m1), umin32(m2, m3));
    }
    __threadfence();                               // release partial stores
    __syncthreads();
    if (tid == 0) slast = (atomicAdd(&cnt[rg], 1) == NSETS - 1);
    __syncthreads();
    if (!slast) return;
    __threadfence();                               // acquire side

    // ---- last set-block of this rg: 16-way merge + exact-f32 gather + epilogue ----
    const unsigned int* pr = partial + (size_t)rg * NSETS * RPRG;
    for (int rr = tid; rr < RPRG; rr += 256) {
        unsigned int m = 0xFFFFFFFFu;
#pragma unroll
        for (int s = 0; s < NSETS; ++s) m = umin32(m, pr[s * RPRG + rr]);
        sentry[rr] = m & 0xFFFu;
    }
    __syncthreads();

    const int rowBase = rg * RPRG;
    for (int u = tid; u < RPRG * 4; u += 256) {    // 512 rows x 4 parts
        int rl = u >> 2, part = u & 3;
        int row = rowBase + rl;
        if (row < nrows) {
            int e = (int)sentry[rl];
            const float4* wr = (const float4*)(w + (size_t)e * DIM + part * 16);
            const float4* xr = (const float4*)(x + (size_t)row * DIM + part * 16);
            float4* qo = (float4*)(qout + (size_t)row * DIM + part * 16);
            float4* lo = (float4*)(lout + (size_t)row * DIM + part * 16);
#pragma unroll
            for (int j = 0; j < 4; ++j) {
                float4 q = wr[j], xv = xr[j], df, qv, lv;
                df.x = q.x - xv.x; df.y = q.y - xv.y; df.z = q.z - xv.z; df.w = q.w - xv.w;
                qv.x = xv.x + df.x; qv.y = xv.y + df.y; qv.z = xv.z + df.z; qv.w = xv.w + df.w;
                float sx = df.x*df.x, sy = df.y*df.y, sz = df.z*df.z, sw = df.w*df.w;
                lv.x = sx + 0.25f*sx; lv.y = sy + 0.25f*sy;
                lv.z = sz + 0.25f*sz; lv.w = sw + 0.25f*sw;
                qo[j] = qv;
                lo[j] = lv;
            }
        }
    }
}

extern "C" void kernel_launch(void* const* d_in, const int* in_sizes, int n_in,
                              void* d_out, int out_size, void* d_ws, size_t ws_size,
                              hipStream_t stream) {
    const float* x = (const float*)d_in[0];   // [8,4096,64] f32
    const float* w = (const float*)d_in[1];   // [4096,64] f32
    const int nrows = in_sizes[0] / DIM;      // 32768
    float* qout = (float*)d_out;
    float* lout = (float*)d_out + (size_t)nrows * DIM;

    // ws: Wp 512K | a5p 128K | xp 4M | partial 2M | cnt 256B
    char* wsp = (char*)d_ws;
    bf16x8* Wp  = (bf16x8*)wsp;                 wsp += (size_t)NCHUNK * 256 * 16;
    bf16x8* a5p = (bf16x8*)wsp;                 wsp += (size_t)NCHUNK * 64 * 16;
    bf16x8* xp  = (bf16x8*)wsp;                 wsp += (size_t)nrows * DIM * 2;
    unsigned int* partial = (unsigned int*)wsp; wsp += (size_t)(nrows / RPRG) * NSETS * RPRG * 4;
    int* cnt = (int*)wsp;

    const int nrg = nrows / RPRG;               // 64
    const int ntiles = nrows / 32;              // 1024
    int prep_thr = NCHUNK * 64 + ntiles * 64;
    prep<<<(prep_thr + 255) / 256, 256, 0, stream>>>(w, x, Wp, a5p, xp, cnt, nrows, nrg);

    vq_main<<<nrg * NSETS, 256, 0, stream>>>(Wp, a5p, xp, x, w, partial, cnt,
                                             qout, lout, nrows);
}

// Round 11
// 36.594 us; speedup vs baseline: 4.2294x; 4.2294x over previous
//
#include <hip/hip_runtime.h>

typedef __bf16 bf16x8 __attribute__((ext_vector_type(8)));
typedef float f32x16 __attribute__((ext_vector_type(16)));

#define N_EMB 4096
#define DIM 64
#define NCHUNK 128            // 4096 entries / 32 per chunk
#define NSETS 16              // 16 sets x 8 chunks; block owns one set
#define NW 8                  // waves per block; wave wv owns chunk set*8+wv
#define T_TILES 16            // x-tiles (32 rows) per row-group
#define NPAIR 8               // staged in pairs of tiles (8KB per stage)
#define RPRG (T_TILES * 32)   // 512 rows per row-group
#define BIAS 0.0625f          // distances > 0 -> uint order == float order (R4-R10)

__device__ __forceinline__ unsigned int umin32(unsigned int a, unsigned int b) {
    return a < b ? a : b;
}
__device__ __forceinline__ unsigned int umin3(unsigned int a, unsigned int b,
                                              unsigned int c) {
    return umin32(umin32(a, b), c);    // v_min3_u32
}
__device__ __forceinline__ void gload_lds16(const void* g, void* l) {
    __builtin_amdgcn_global_load_lds(
        (const __attribute__((address_space(1))) unsigned int*)g,
        (__attribute__((address_space(3))) unsigned int*)l, 16, 0, 0);
}

// ---------------- prep: W-pack + a5-norm-frag + x-pack (layouts validated R2-R10) ----
//  Wp[(g*4+s)*64+l][e] = bf16(-2 W[g*32+l%32][s*16+(l/32)*8+e])   (A-frag linear)
//  a5p[g*64+l] = {bf16(||W[g*32+l]||^2+BIAS),0..} l<32, else 0    (a5 x e0 C-init fold)
//  xp[gt*256+s*64+l][e] = bf16(x[gt*32+l%32][s*16+(l/32)*8+e])    (B-frag linear)
__global__ void prep(const float* __restrict__ w, const float* __restrict__ x,
                     bf16x8* __restrict__ Wp, bf16x8* __restrict__ a5p,
                     bf16x8* __restrict__ xp, int nrows) {
    int id = blockIdx.x * blockDim.x + threadIdx.x;
    if (id < NCHUNK * 64) {
        int g = id >> 6, l = id & 63;
        int hi = l >> 5;
        const float* wr = w + (size_t)((g << 5) + (l & 31)) * DIM + hi * 8;
        float ss = 0.f;
#pragma unroll
        for (int s = 0; s < 4; ++s) {
            const float4* p = (const float4*)(wr + s * 16);
            float4 v0 = p[0], v1 = p[1];
            ss += v0.x*v0.x + v0.y*v0.y + v0.z*v0.z + v0.w*v0.w;
            ss += v1.x*v1.x + v1.y*v1.y + v1.z*v1.z + v1.w*v1.w;
            bf16x8 o;
            o[0]=(__bf16)(-2.f*v0.x); o[1]=(__bf16)(-2.f*v0.y);
            o[2]=(__bf16)(-2.f*v0.z); o[3]=(__bf16)(-2.f*v0.w);
            o[4]=(__bf16)(-2.f*v1.x); o[5]=(__bf16)(-2.f*v1.y);
            o[6]=(__bf16)(-2.f*v1.z); o[7]=(__bf16)(-2.f*v1.w);
            Wp[(g * 4 + s) * 64 + l] = o;
        }
        ss += __shfl_xor(ss, 32, 64);
        bf16x8 a5 = {};
        if (l < 32) a5[0] = (__bf16)(ss + BIAS);
        a5p[g * 64 + l] = a5;
    } else {
        int id2 = id - NCHUNK * 64;
        int gt = id2 >> 6, l = id2 & 63;
        if (gt < nrows / 32) {
            int row = gt * 32 + (l & 31);
            const float* xr = x + (size_t)row * DIM + (l >> 5) * 8;
#pragma unroll
            for (int s = 0; s < 4; ++s) {
                const float4* p = (const float4*)(xr + s * 16);
                float4 v0 = p[0], v1 = p[1];
                bf16x8 o;
                o[0]=(__bf16)v0.x; o[1]=(__bf16)v0.y; o[2]=(__bf16)v0.z; o[3]=(__bf16)v0.w;
                o[4]=(__bf16)v1.x; o[5]=(__bf16)v1.y; o[6]=(__bf16)v1.z; o[7]=(__bf16)v1.w;
                xp[(size_t)gt * 256 + s * 64 + l] = o;
            }
        }
    }
}

// ---------------- main: W-regs, deep LDS ring for x, winners via LDS ----------------
__global__ void __launch_bounds__(512) vq_main(
    const bf16x8* __restrict__ Wp, const bf16x8* __restrict__ a5p,
    const bf16x8* __restrict__ xp, unsigned int* __restrict__ partial, int nrows) {
    __shared__ bf16x8 buf[8][256];                 // 32KB: ring of 4 tile-PAIRS
    __shared__ unsigned int wmerge[NW][RPRG];      // 16KB per-wave winners

    const int tid  = threadIdx.x;
    const int wv   = tid >> 6;
    const int lane = tid & 63;
    const int li   = lane & 31;
    const int hi   = lane >> 5;
    const int set  = blockIdx.x >> 6;              // bid = set*64 + rg:
    const int rg   = blockIdx.x & 63;              //   same-rg blocks share XCD rg%8
    const int c    = set * NW + wv;                // this wave's chunk, fixed
    const int tbase = rg * T_TILES;

    // ---- W: one chunk per wave, loaded once, register-resident ----
    const bf16x8* ap = Wp + (size_t)c * 256 + lane;
    const bf16x8 a0 = ap[0], a1 = ap[64], a2 = ap[128], a3 = ap[192];
    const bf16x8 a5 = a5p[(size_t)c * 64 + lane];
    bf16x8 xone = {};
    if (hi == 0) xone[0] = (__bf16)1.0f;           // B5 = e_0
    const f32x16 zacc = {};
    // hoisted norm fold: cinit[m][*] = ||w_m||^2 + BIAS (loop-invariant C operand)
    const f32x16 cinit = __builtin_amdgcn_mfma_f32_32x32x16_bf16(a5, xone, zacc, 0, 0, 0);

    // stage pair q (rotated by set): tiles {2eq, 2eq+1} -> ring slot pair (q&3)
    #define STAGE(q) do { \
        int eq_ = ((q) + set) & (NPAIR - 1); \
        gload_lds16((const char*)(xp + (size_t)(tbase + 2 * eq_) * 256) + tid * 16, \
                    (char*)buf + (((q) & 3) * 2) * 4096 + wv * 1024); \
    } while (0)

    STAGE(0); STAGE(1);
    asm volatile("s_waitcnt vmcnt(0)" ::: "memory");
    __builtin_amdgcn_s_barrier();

    for (int p = 0; p < NPAIR; ++p) {
        if (p + 2 < NPAIR) STAGE(p + 2);           // only VMEM op in the loop
        const int ep = (p + set) & (NPAIR - 1);
        const char* base = (const char*)buf + ((p & 3) * 2) * 4096;
#pragma unroll
        for (int tt = 0; tt < 2; ++tt) {
            const bf16x8* bv = (const bf16x8*)(base + tt * 4096);
            bf16x8 b0 = bv[lane], b1 = bv[64 + lane];
            bf16x8 b2 = bv[128 + lane], b3 = bv[192 + lane];
            f32x16 acc = __builtin_amdgcn_mfma_f32_32x32x16_bf16(a0, b0, cinit, 0, 0, 0);
            acc = __builtin_amdgcn_mfma_f32_32x32x16_bf16(a1, b1, acc, 0, 0, 0);
            acc = __builtin_amdgcn_mfma_f32_32x32x16_bf16(a2, b2, acc, 0, 0, 0);
            acc = __builtin_amdgcn_mfma_f32_32x32x16_bf16(a3, b3, acc, 0, 0, 0);

            unsigned int tb[16];
#pragma unroll
            for (int r = 0; r < 16; ++r)
                tb[r] = (__builtin_bit_cast(unsigned int, acc[r]) & 0xFFFFFFE0u)
                        | (unsigned int)r;
            unsigned int g0 = umin3(tb[0], tb[1], tb[2]);
            unsigned int g1 = umin3(tb[3], tb[4], tb[5]);
            unsigned int g2 = umin3(tb[6], tb[7], tb[8]);
            unsigned int g3 = umin3(tb[9], tb[10], tb[11]);
            unsigned int g4 = umin3(tb[12], tb[13], tb[14]);
            unsigned int best = umin3(umin3(g0, g1, g2), umin3(g3, g4, tb[15]),
                                      0xFFFFFFFFu);
            best |= (unsigned int)hi << 4;         // bit 4 free (tags are 4 bits)
            unsigned int ob = (unsigned int)__shfl_xor((int)best, 32, 64);
            best = umin32(best, ob);
            // reconstruct 12-bit entry, pack (dist | entry) for pure-min merges
            unsigned int r4 = best & 15u, hh = (best >> 4) & 1u;
            unsigned int entry = (unsigned int)c * 32 + (r4 & 3u) + ((r4 >> 2) << 3)
                                 + (hh << 2);
            if (lane < 32)
                wmerge[wv][(2 * ep + tt) * 32 + li] = (best & 0xFFFFF000u) | entry;
        }
        // counted wait: pair p+1 retired (only pair p+2 may remain in flight)
        if (p + 2 < NPAIR) asm volatile("s_waitcnt vmcnt(1)" ::: "memory");
        else               asm volatile("s_waitcnt vmcnt(0)" ::: "memory");
        __builtin_amdgcn_s_barrier();
    }
    #undef STAGE

    __syncthreads();                               // wmerge LDS visibility
    // cross-wave merge: 8 -> 1 slot per row; coalesced 2KB store (no fences!)
    {
        unsigned int m = wmerge[0][tid & 511];
#pragma unroll
        for (int q = 1; q < NW; ++q) m = umin32(m, wmerge[q][tid & 511]);
        partial[((size_t)rg * NSETS + set) * RPRG + (tid & 511)] = m;
    }
}

// ---------------- fin: 16-way min per row, gather, epilogue ----------------
__global__ void __launch_bounds__(256) vq_fin(
    const float* __restrict__ x, const float* __restrict__ w,
    const unsigned int* __restrict__ partial,
    float* __restrict__ qout, float* __restrict__ lout, int nrows) {
    __shared__ unsigned int red[4][64];
    __shared__ int sentry[64];
    const int t  = threadIdx.x;
    const int r0 = blockIdx.x * 64;

    {   // phase 1: thread (grp, rl) min-reduces 4 of the 16 set-slots for one row
        int rl = t & 63, grp = t >> 6;
        int row = r0 + rl;
        if (row >= nrows) row = nrows - 1;
        int rgi = row >> 9, rir = row & 511;
        const unsigned int* p = partial + ((size_t)rgi * NSETS + grp * 4) * RPRG + rir;
        unsigned int m = umin32(umin32(p[0], p[RPRG]),
                                umin32(p[2 * RPRG], p[3 * RPRG]));
        red[grp][rl] = m;
    }
    __syncthreads();
    if (t < 64) {
        unsigned int a = red[0][t], b = red[1][t], c = red[2][t], d = red[3][t];
        sentry[t] = (int)(umin32(umin32(a, b), umin32(c, d)) & 0xFFFu);
    }
    __syncthreads();

    {   // phase 2: 64 rows x 4 parts; exact f32 gather + quantized/loss write
        int rl = t >> 2, part = t & 3;
        int row = r0 + rl;
        if (row < nrows) {
            int e = sentry[rl];
            const float4* wr = (const float4*)(w + (size_t)e * DIM + part * 16);
            const float4* xr = (const float4*)(x + (size_t)row * DIM + part * 16);
            float4* qo = (float4*)(qout + (size_t)row * DIM + part * 16);
            float4* lo = (float4*)(lout + (size_t)row * DIM + part * 16);
#pragma unroll
            for (int j = 0; j < 4; ++j) {
                float4 q = wr[j], xv = xr[j], df, qv, lv;
                df.x = q.x - xv.x; df.y = q.y - xv.y; df.z = q.z - xv.z; df.w = q.w - xv.w;
                qv.x = xv.x + df.x; qv.y = xv.y + df.y; qv.z = xv.z + df.z; qv.w = xv.w + df.w;
                float sx = df.x*df.x, sy = df.y*df.y, sz = df.z*df.z, sw = df.w*df.w;
                lv.x = sx + 0.25f*sx; lv.y = sy + 0.25f*sy;
                lv.z = sz + 0.25f*sz; lv.w = sw + 0.25f*sw;
                qo[j] = qv;
                lo[j] = lv;
            }
        }
    }
}

extern "C" void kernel_launch(void* const* d_in, const int* in_sizes, int n_in,
                              void* d_out, int out_size, void* d_ws, size_t ws_size,
                              hipStream_t stream) {
    const float* x = (const float*)d_in[0];   // [8,4096,64] f32
    const float* w = (const float*)d_in[1];   // [4096,64] f32
    const int nrows = in_sizes[0] / DIM;      // 32768
    float* qout = (float*)d_out;
    float* lout = (float*)d_out + (size_t)nrows * DIM;

    // ws: Wp 512K | a5p 128K | xp 4M | partial 2M
    char* wsp = (char*)d_ws;
    bf16x8* Wp  = (bf16x8*)wsp;                 wsp += (size_t)NCHUNK * 256 * 16;
    bf16x8* a5p = (bf16x8*)wsp;                 wsp += (size_t)NCHUNK * 64 * 16;
    bf16x8* xp  = (bf16x8*)wsp;                 wsp += (size_t)nrows * DIM * 2;
    unsigned int* partial = (unsigned int*)wsp; // (nrows/RPRG)*NSETS*RPRG*4 = 2MB

    const int ntiles = nrows / 32;              // 1024
    int prep_thr = NCHUNK * 64 + ntiles * 64;
    prep<<<(prep_thr + 255) / 256, 256, 0, stream>>>(w, x, Wp, a5p, xp, nrows);

    const int nrg = nrows / RPRG;               // 64
    vq_main<<<NSETS * nrg, 512, 0, stream>>>(Wp, a5p, xp, partial, nrows);

    vq_fin<<<(nrows + 63) / 64, 256, 0, stream>>>(x, w, partial, qout, lout, nrows);
}

// Round 12
// 35.117 us; speedup vs baseline: 4.4073x; 1.0421x over previous
//
#include <hip/hip_runtime.h>

typedef __bf16 bf16x8 __attribute__((ext_vector_type(8)));
typedef float f32x16 __attribute__((ext_vector_type(16)));

#define N_EMB 4096
#define DIM 64
#define NCHUNK 128            // 4096 entries / 32 per chunk
#define NSB 4                 // set-blocks; block owns 32 chunks (8 waves x 4)
#define NC 4                  // chunks per wave, register-resident
#define NW 8                  // waves per block
#define T_TILES 16            // x-tiles (32 rows) per row-group
#define RPRG (T_TILES * 32)   // 512 rows per row-group
#define BIAS 0.0625f          // distances > 0 -> uint order == float order (R4-R11)

__device__ __forceinline__ unsigned int umin32(unsigned int a, unsigned int b) {
    return a < b ? a : b;
}
__device__ __forceinline__ unsigned int umin3(unsigned int a, unsigned int b,
                                              unsigned int c) {
    return umin32(umin32(a, b), c);    // v_min3_u32
}
__device__ __forceinline__ void gload_lds16(const void* g, void* l) {
    __builtin_amdgcn_global_load_lds(
        (const __attribute__((address_space(1))) unsigned int*)g,
        (__attribute__((address_space(3))) unsigned int*)l, 16, 0, 0);
}

// ---------------- prep: W-pack + a5-norm-frag + x-pack (layouts validated R2-R11) ----
//  Wp[(g*4+s)*64+l][e] = bf16(-2 W[g*32+l%32][s*16+(l/32)*8+e])   (A-frag linear)
//  a5p[g*64+l] = {bf16(||W[g*32+l]||^2+BIAS),0..} l<32, else 0    (a5 x e0 C-init fold)
//  xp[gt*256+s*64+l][e] = bf16(x[gt*32+l%32][s*16+(l/32)*8+e])    (B-frag linear)
__global__ void prep(const float* __restrict__ w, const float* __restrict__ x,
                     bf16x8* __restrict__ Wp, bf16x8* __restrict__ a5p,
                     bf16x8* __restrict__ xp, int nrows) {
    int id = blockIdx.x * blockDim.x + threadIdx.x;
    if (id < NCHUNK * 64) {
        int g = id >> 6, l = id & 63;
        int hi = l >> 5;
        const float* wr = w + (size_t)((g << 5) + (l & 31)) * DIM + hi * 8;
        float ss = 0.f;
#pragma unroll
        for (int s = 0; s < 4; ++s) {
            const float4* p = (const float4*)(wr + s * 16);
            float4 v0 = p[0], v1 = p[1];
            ss += v0.x*v0.x + v0.y*v0.y + v0.z*v0.z + v0.w*v0.w;
            ss += v1.x*v1.x + v1.y*v1.y + v1.z*v1.z + v1.w*v1.w;
            bf16x8 o;
            o[0]=(__bf16)(-2.f*v0.x); o[1]=(__bf16)(-2.f*v0.y);
            o[2]=(__bf16)(-2.f*v0.z); o[3]=(__bf16)(-2.f*v0.w);
            o[4]=(__bf16)(-2.f*v1.x); o[5]=(__bf16)(-2.f*v1.y);
            o[6]=(__bf16)(-2.f*v1.z); o[7]=(__bf16)(-2.f*v1.w);
            Wp[(g * 4 + s) * 64 + l] = o;
        }
        ss += __shfl_xor(ss, 32, 64);
        bf16x8 a5 = {};
        if (l < 32) a5[0] = (__bf16)(ss + BIAS);
        a5p[g * 64 + l] = a5;
    } else {
        int id2 = id - NCHUNK * 64;
        int gt = id2 >> 6, l = id2 & 63;
        if (gt < nrows / 32) {
            int row = gt * 32 + (l & 31);
            const float* xr = x + (size_t)row * DIM + (l >> 5) * 8;
#pragma unroll
            for (int s = 0; s < 4; ++s) {
                const float4* p = (const float4*)(xr + s * 16);
                float4 v0 = p[0], v1 = p[1];
                bf16x8 o;
                o[0]=(__bf16)v0.x; o[1]=(__bf16)v0.y; o[2]=(__bf16)v0.z; o[3]=(__bf16)v0.w;
                o[4]=(__bf16)v1.x; o[5]=(__bf16)v1.y; o[6]=(__bf16)v1.z; o[7]=(__bf16)v1.w;
                xp[(size_t)gt * 256 + s * 64 + l] = o;
            }
        }
    }
}

// ---------------- main: 4 chunks/wave in regs; wave-private LDS ring; no barriers ----
__global__ void __launch_bounds__(512) vq_main(
    const bf16x8* __restrict__ Wp, const bf16x8* __restrict__ a5p,
    const bf16x8* __restrict__ xp, unsigned int* __restrict__ partial, int nrows) {
    __shared__ bf16x8 buf[NW][2][256];             // 64KB: per-wave private 2-slot ring
    __shared__ unsigned int wmerge[NW][RPRG];      // 16KB per-wave winners

    const int tid  = threadIdx.x;
    const int wv   = tid >> 6;
    const int lane = tid & 63;
    const int li   = lane & 31;
    const int hi   = lane >> 5;
    const int s    = blockIdx.x >> 6;              // set-block 0..3
    const int rg   = blockIdx.x & 63;              // same-rg blocks share XCD rg%8
    const int c0   = s * (NW * NC) + wv * NC;      // this wave's 4 chunks
    const int tbase = rg * T_TILES;

    // ---- W: 4 chunks, loaded once; norm fold hoisted into 4 C-init fragments ----
    bf16x8 a[NC][4];
    f32x16 cinit[NC];
    {
        bf16x8 xone = {};
        if (hi == 0) xone[0] = (__bf16)1.0f;       // B5 = e_0
        const f32x16 zacc = {};
#pragma unroll
        for (int ck = 0; ck < NC; ++ck) {
            const bf16x8* ap = Wp + (size_t)(c0 + ck) * 256 + lane;
            a[ck][0] = ap[0]; a[ck][1] = ap[64]; a[ck][2] = ap[128]; a[ck][3] = ap[192];
            bf16x8 a5 = a5p[(size_t)(c0 + ck) * 64 + lane];
            cinit[ck] = __builtin_amdgcn_mfma_f32_32x32x16_bf16(a5, xone, zacc, 0, 0, 0);
        }
    }

    // stage tile t into this wave's slot (t&1): 4 x 1KB spans (wave-uniform dst base)
    #define STAGE(t) do { \
        const char* src_ = (const char*)(xp + (size_t)(tbase + (t)) * 256) + lane * 16; \
        char* dst_ = (char*)&buf[wv][(t) & 1][0]; \
        gload_lds16(src_,        dst_); \
        gload_lds16(src_ + 1024, dst_ + 1024); \
        gload_lds16(src_ + 2048, dst_ + 2048); \
        gload_lds16(src_ + 3072, dst_ + 3072); \
    } while (0)

    STAGE(0); STAGE(1);                            // 8 outstanding

    for (int t = 0; t < T_TILES; ++t) {
        asm volatile("s_waitcnt vmcnt(4)" ::: "memory");   // stage(t) landed
        const bf16x8* bv = &buf[wv][t & 1][0];
        bf16x8 b0 = bv[lane], b1 = bv[64 + lane];
        bf16x8 b2 = bv[128 + lane], b3 = bv[192 + lane];

        // 16 MFMAs: 4 independent chains, one per register-resident chunk
        f32x16 acc0 = __builtin_amdgcn_mfma_f32_32x32x16_bf16(a[0][0], b0, cinit[0], 0, 0, 0);
        f32x16 acc1 = __builtin_amdgcn_mfma_f32_32x32x16_bf16(a[1][0], b0, cinit[1], 0, 0, 0);
        f32x16 acc2 = __builtin_amdgcn_mfma_f32_32x32x16_bf16(a[2][0], b0, cinit[2], 0, 0, 0);
        f32x16 acc3 = __builtin_amdgcn_mfma_f32_32x32x16_bf16(a[3][0], b0, cinit[3], 0, 0, 0);
        acc0 = __builtin_amdgcn_mfma_f32_32x32x16_bf16(a[0][1], b1, acc0, 0, 0, 0);
        acc1 = __builtin_amdgcn_mfma_f32_32x32x16_bf16(a[1][1], b1, acc1, 0, 0, 0);
        acc2 = __builtin_amdgcn_mfma_f32_32x32x16_bf16(a[2][1], b1, acc2, 0, 0, 0);
        acc3 = __builtin_amdgcn_mfma_f32_32x32x16_bf16(a[3][1], b1, acc3, 0, 0, 0);
        acc0 = __builtin_amdgcn_mfma_f32_32x32x16_bf16(a[0][2], b2, acc0, 0, 0, 0);
        acc1 = __builtin_amdgcn_mfma_f32_32x32x16_bf16(a[1][2], b2, acc1, 0, 0, 0);
        acc2 = __builtin_amdgcn_mfma_f32_32x32x16_bf16(a[2][2], b2, acc2, 0, 0, 0);
        acc3 = __builtin_amdgcn_mfma_f32_32x32x16_bf16(a[3][2], b2, acc3, 0, 0, 0);
        acc0 = __builtin_amdgcn_mfma_f32_32x32x16_bf16(a[0][3], b3, acc0, 0, 0, 0);
        acc1 = __builtin_amdgcn_mfma_f32_32x32x16_bf16(a[1][3], b3, acc1, 0, 0, 0);
        acc2 = __builtin_amdgcn_mfma_f32_32x32x16_bf16(a[2][3], b3, acc2, 0, 0, 0);
        acc3 = __builtin_amdgcn_mfma_f32_32x32x16_bf16(a[3][3], b3, acc3, 0, 0, 0);

        // next-tile stage AFTER the MFMAs (their lgkm wait frees slot t&1 for t+2)
        if (t + 2 < T_TILES) STAGE(t + 2);

        // packed argmin: clear 7 mantissa bits, tag = ck<<5 | hi<<4(later) | r
        unsigned int best = 0xFFFFFFFFu;
        const f32x16* accs[4] = { &acc0, &acc1, &acc2, &acc3 };
#pragma unroll
        for (int ck = 0; ck < NC; ++ck) {
            const f32x16& acc = *accs[ck];
            unsigned int tb[16];
#pragma unroll
            for (int r = 0; r < 16; ++r)
                tb[r] = (__builtin_bit_cast(unsigned int, acc[r]) & 0xFFFFFF80u)
                        | ((unsigned int)ck << 5) | (unsigned int)r;
            unsigned int g0 = umin3(tb[0], tb[1], tb[2]);
            unsigned int g1 = umin3(tb[3], tb[4], tb[5]);
            unsigned int g2 = umin3(tb[6], tb[7], tb[8]);
            unsigned int g3 = umin3(tb[9], tb[10], tb[11]);
            unsigned int g4 = umin3(tb[12], tb[13], tb[14]);
            best = umin3(best, umin3(g0, g1, g2), umin3(g3, g4, tb[15]));
        }
        best |= (unsigned int)hi << 4;
        unsigned int ob = (unsigned int)__shfl_xor((int)best, 32, 64);
        best = umin32(best, ob);
        // reconstruct 12-bit entry, repack (dist | entry) for pure-min merges
        unsigned int r4 = best & 15u, hh = (best >> 4) & 1u, ck2 = (best >> 5) & 3u;
        unsigned int entry = (unsigned int)(c0 + ck2) * 32 + (r4 & 3u)
                             + ((r4 >> 2) << 3) + (hh << 2);
        if (lane < 32) wmerge[wv][t * 32 + li] = (best & 0xFFFFF000u) | entry;
    }
    #undef STAGE

    __syncthreads();                               // first barrier since prologue
    // cross-wave merge: 8 -> 1 slot per row; coalesced 2KB store
    {
        int rr = tid & 511;
        unsigned int m = wmerge[0][rr];
#pragma unroll
        for (int q = 1; q < NW; ++q) m = umin32(m, wmerge[q][rr]);
        partial[((size_t)rg * NSB + s) * RPRG + rr] = m;
    }
}

// ---------------- fin: 4-way min per row, gather, epilogue ----------------
__global__ void __launch_bounds__(256) vq_fin(
    const float* __restrict__ x, const float* __restrict__ w,
    const unsigned int* __restrict__ partial,
    float* __restrict__ qout, float* __restrict__ lout, int nrows) {
    __shared__ unsigned int red[4][64];
    __shared__ int sentry[64];
    const int t  = threadIdx.x;
    const int r0 = blockIdx.x * 64;

    {   // phase 1: thread (grp, rl) reads set-slot grp for one row (coalesced)
        int rl = t & 63, grp = t >> 6;
        int row = r0 + rl;
        if (row >= nrows) row = nrows - 1;
        int rgi = row >> 9, rir = row & 511;
        red[grp][rl] = partial[((size_t)rgi * NSB + grp) * RPRG + rir];
    }
    __syncthreads();
    if (t < 64) {
        unsigned int a = red[0][t], b = red[1][t], c = red[2][t], d = red[3][t];
        sentry[t] = (int)(umin32(umin32(a, b), umin32(c, d)) & 0xFFFu);
    }
    __syncthreads();

    {   // phase 2: 64 rows x 4 parts; exact f32 gather + quantized/loss write
        int rl = t >> 2, part = t & 3;
        int row = r0 + rl;
        if (row < nrows) {
            int e = sentry[rl];
            const float4* wr = (const float4*)(w + (size_t)e * DIM + part * 16);
            const float4* xr = (const float4*)(x + (size_t)row * DIM + part * 16);
            float4* qo = (float4*)(qout + (size_t)row * DIM + part * 16);
            float4* lo = (float4*)(lout + (size_t)row * DIM + part * 16);
#pragma unroll
            for (int j = 0; j < 4; ++j) {
                float4 q = wr[j], xv = xr[j], df, qv, lv;
                df.x = q.x - xv.x; df.y = q.y - xv.y; df.z = q.z - xv.z; df.w = q.w - xv.w;
                qv.x = xv.x + df.x; qv.y = xv.y + df.y; qv.z = xv.z + df.z; qv.w = xv.w + df.w;
                float sx = df.x*df.x, sy = df.y*df.y, sz = df.z*df.z, sw = df.w*df.w;
                lv.x = sx + 0.25f*sx; lv.y = sy + 0.25f*sy;
                lv.z = sz + 0.25f*sz; lv.w = sw + 0.25f*sw;
                qo[j] = qv;
                lo[j] = lv;
            }
        }
    }
}

extern "C" void kernel_launch(void* const* d_in, const int* in_sizes, int n_in,
                              void* d_out, int out_size, void* d_ws, size_t ws_size,
                              hipStream_t stream) {
    const float* x = (const float*)d_in[0];   // [8,4096,64] f32
    const float* w = (const float*)d_in[1];   // [4096,64] f32
    const int nrows = in_sizes[0] / DIM;      // 32768
    float* qout = (float*)d_out;
    float* lout = (float*)d_out + (size_t)nrows * DIM;

    // ws: Wp 512K | a5p 128K | xp 4M | partial 512K
    char* wsp = (char*)d_ws;
    bf16x8* Wp  = (bf16x8*)wsp;                 wsp += (size_t)NCHUNK * 256 * 16;
    bf16x8* a5p = (bf16x8*)wsp;                 wsp += (size_t)NCHUNK * 64 * 16;
    bf16x8* xp  = (bf16x8*)wsp;                 wsp += (size_t)nrows * DIM * 2;
    unsigned int* partial = (unsigned int*)wsp; // (nrows/RPRG)*NSB*RPRG*4 = 512KB

    const int ntiles = nrows / 32;              // 1024
    int prep_thr = NCHUNK * 64 + ntiles * 64;
    prep<<<(prep_thr + 255) / 256, 256, 0, stream>>>(w, x, Wp, a5p, xp, nrows);

    const int nrg = nrows / RPRG;               // 64
    vq_main<<<NSB * nrg, 512, 0, stream>>>(Wp, a5p, xp, partial, nrows);

    vq_fin<<<(nrows + 63) / 64, 256, 0, stream>>>(x, w, partial, qout, lout, nrows);
}